// Round 4
// baseline (976.840 us; speedup 1.0000x reference)
//
#include <hip/hip_runtime.h>

// PropLayer: 3 weighted segment-sums + passthrough.
// Fused CSR build (concatenated counters, single global scan, global positions)
// + per-graph gathers ordered for L3 locality.
// out layout (floats): [paper N_P*256][author N_A*256][venue N_V*256]
// counter layout:      [author 0..N_A) | pi N_A..N_A+N_V) | hp ..+N_V)

// ---------------- fused CSR build ----------------

__global__ __launch_bounds__(256) void hist_all_kernel(
    const int* __restrict__ wb_dst, int E_wb,
    const int* __restrict__ pi_dst, int E_pi,
    const int* __restrict__ hp_dst, int E_hp,
    int n_author, int n_venue, int* __restrict__ counts)
{
    int e = blockIdx.x * blockDim.x + threadIdx.x;
    int idx;
    if (e < E_wb)                    idx = wb_dst[e];
    else if (e < E_wb + E_pi)        idx = n_author + pi_dst[e - E_wb];
    else if (e < E_wb + E_pi + E_hp) idx = n_author + n_venue + hp_dst[e - E_wb - E_pi];
    else return;
    atomicAdd(&counts[idx], 1);
}

__global__ __launch_bounds__(256) void scan_block_sums(const int* __restrict__ counts, int n,
                                                       int* __restrict__ partials) {
    __shared__ int s[256];
    int i = blockIdx.x * 256 + threadIdx.x;
    s[threadIdx.x] = (i < n) ? counts[i] : 0;
    __syncthreads();
    for (int st = 128; st > 0; st >>= 1) {
        if (threadIdx.x < st) s[threadIdx.x] += s[threadIdx.x + st];
        __syncthreads();
    }
    if (threadIdx.x == 0) partials[blockIdx.x] = s[0];
}

__global__ void scan_partials_serial(int* partials, int m) {
    if (blockIdx.x == 0 && threadIdx.x == 0) {
        int acc = 0;
        for (int i = 0; i < m; ++i) { int v = partials[i]; partials[i] = acc; acc += v; }
    }
}

__global__ __launch_bounds__(256) void scan_write_offs(const int* __restrict__ counts, int n,
                                                       const int* __restrict__ partials,
                                                       int* __restrict__ offs) {
    __shared__ int s[256];
    int i = blockIdx.x * 256 + threadIdx.x;
    int v = (i < n) ? counts[i] : 0;
    s[threadIdx.x] = v;
    __syncthreads();
    for (int st = 1; st < 256; st <<= 1) {
        int t = (threadIdx.x >= st) ? s[threadIdx.x - st] : 0;
        __syncthreads();
        s[threadIdx.x] += t;
        __syncthreads();
    }
    int incl = s[threadIdx.x];
    if (i < n) offs[i] = partials[blockIdx.x] + (incl - v);
    if (i == n - 1) offs[n] = partials[blockIdx.x] + incl;
}

// writes dst-sorted (src, combined-weight) at GLOBAL positions
__global__ __launch_bounds__(256) void fill_all_kernel(
    const int* __restrict__ wb_dst, const int* __restrict__ wb_src,
    const float* __restrict__ wb_w, int E_wb,
    const int* __restrict__ pi_dst, const int* __restrict__ pi_src,
    const float* __restrict__ pi_alpha, const float* __restrict__ pi_w, int E_pi,
    const int* __restrict__ hp_dst, const int* __restrict__ hp_src,
    const float* __restrict__ hp_feat, const float* __restrict__ hp_alpha, int E_hp,
    int n_author, int n_venue,
    const int* __restrict__ g, int* __restrict__ cursor,
    int* __restrict__ srcs_out, float* __restrict__ ws_out)
{
    int e = blockIdx.x * blockDim.x + threadIdx.x;
    int idx, src; float w;
    if (e < E_wb) {
        idx = wb_dst[e]; src = wb_src[e]; w = wb_w[e];
    } else if (e < E_wb + E_pi) {
        int i = e - E_wb;
        idx = n_author + pi_dst[i]; src = pi_src[i]; w = pi_alpha[i] * pi_w[i];
    } else if (e < E_wb + E_pi + E_hp) {
        int i = e - E_wb - E_pi;
        idx = n_author + n_venue + hp_dst[i]; src = hp_src[i]; w = hp_feat[i] * hp_alpha[i];
    } else return;
    int pos = g[idx] + atomicAdd(&cursor[idx], 1);
    srcs_out[pos] = src;
    ws_out[pos]   = w;
}

// ---------------- gathers ----------------

// one 64-lane wave per author row, unroll x4
__global__ __launch_bounds__(256) void gather_author_kernel(
    const float* __restrict__ paper_h,
    const int* __restrict__ offs,
    const int* __restrict__ srcs, const float* __restrict__ ws,
    float* __restrict__ out, int n_rows)
{
    int tid = blockIdx.x * blockDim.x + threadIdx.x;
    int row = tid >> 6, lane = tid & 63;
    if (row >= n_rows) return;
    int beg = offs[row], end = offs[row + 1];
    float ax = 0.f, ay = 0.f, az = 0.f, aw = 0.f;
    int p = beg;
    for (; p + 4 <= end; p += 4) {
        int s0 = srcs[p], s1 = srcs[p+1], s2 = srcs[p+2], s3 = srcs[p+3];
        float w0 = ws[p], w1 = ws[p+1], w2 = ws[p+2], w3 = ws[p+3];
        float4 v0 = *(reinterpret_cast<const float4*>(paper_h + (size_t)s0 * 256) + lane);
        float4 v1 = *(reinterpret_cast<const float4*>(paper_h + (size_t)s1 * 256) + lane);
        float4 v2 = *(reinterpret_cast<const float4*>(paper_h + (size_t)s2 * 256) + lane);
        float4 v3 = *(reinterpret_cast<const float4*>(paper_h + (size_t)s3 * 256) + lane);
        ax += v0.x*w0 + v1.x*w1 + v2.x*w2 + v3.x*w3;
        ay += v0.y*w0 + v1.y*w1 + v2.y*w2 + v3.y*w3;
        az += v0.z*w0 + v1.z*w1 + v2.z*w2 + v3.z*w3;
        aw += v0.w*w0 + v1.w*w1 + v2.w*w2 + v3.w*w3;
    }
    for (; p < end; ++p) {
        int s = srcs[p]; float w = ws[p];
        float4 v = *(reinterpret_cast<const float4*>(paper_h + (size_t)s * 256) + lane);
        ax += v.x*w; ay += v.y*w; az += v.z*w; aw += v.w*w;
    }
    float4 o = {ax, ay, az, aw};
    *(reinterpret_cast<float4*>(out + (size_t)row * 256) + lane) = o;
}

// SPLIT waves per venue row, single graph, atomic combine into zeroed out
template<int SPLIT>
__global__ __launch_bounds__(256) void gather_venue_part(
    const float* __restrict__ h,
    const int* __restrict__ offs,          // already offset to this graph's counters
    const int* __restrict__ srcs, const float* __restrict__ ws,
    float* __restrict__ out, int n_rows)
{
    int tid = blockIdx.x * blockDim.x + threadIdx.x;
    int wid = tid >> 6, lane = tid & 63;
    int row = wid / SPLIT, part = wid % SPLIT;
    if (row >= n_rows) return;
    int beg0 = offs[row], end0 = offs[row + 1];
    int total = end0 - beg0;
    int per = (total + SPLIT - 1) / SPLIT;
    int beg = beg0 + part * per;
    int end = min(beg + per, end0);
    if (beg >= end) return;
    float ax = 0.f, ay = 0.f, az = 0.f, aw = 0.f;
    int p = beg;
    for (; p + 4 <= end; p += 4) {
        int s0 = srcs[p], s1 = srcs[p+1], s2 = srcs[p+2], s3 = srcs[p+3];
        float w0 = ws[p], w1 = ws[p+1], w2 = ws[p+2], w3 = ws[p+3];
        float4 v0 = *(reinterpret_cast<const float4*>(h + (size_t)s0 * 256) + lane);
        float4 v1 = *(reinterpret_cast<const float4*>(h + (size_t)s1 * 256) + lane);
        float4 v2 = *(reinterpret_cast<const float4*>(h + (size_t)s2 * 256) + lane);
        float4 v3 = *(reinterpret_cast<const float4*>(h + (size_t)s3 * 256) + lane);
        ax += v0.x*w0 + v1.x*w1 + v2.x*w2 + v3.x*w3;
        ay += v0.y*w0 + v1.y*w1 + v2.y*w2 + v3.y*w3;
        az += v0.z*w0 + v1.z*w1 + v2.z*w2 + v3.z*w3;
        aw += v0.w*w0 + v1.w*w1 + v2.w*w2 + v3.w*w3;
    }
    for (; p < end; ++p) {
        int s = srcs[p]; float w = ws[p];
        float4 v = *(reinterpret_cast<const float4*>(h + (size_t)s * 256) + lane);
        ax += v.x*w; ay += v.y*w; az += v.z*w; aw += v.w*w;
    }
    float* dst = out + (size_t)row * 256 + (size_t)lane * 4;
    unsafeAtomicAdd(dst + 0, ax);
    unsafeAtomicAdd(dst + 1, ay);
    unsafeAtomicAdd(dst + 2, az);
    unsafeAtomicAdd(dst + 3, aw);
}

// ---------------- fallback (atomic scatter path) ----------------

__global__ __launch_bounds__(256) void edge_scatter_kernel(
    const float* __restrict__ src_h, const int* __restrict__ src_idx,
    const int* __restrict__ dst_idx, const float* __restrict__ w0,
    const float* __restrict__ w1, float* __restrict__ out, int n_edges)
{
    int tid = blockIdx.x * blockDim.x + threadIdx.x;
    int e = tid >> 6;
    if (e >= n_edges) return;
    int lane = tid & 63;
    float w = w0[e];
    if (w1) w *= w1[e];
    const float4 v = *(reinterpret_cast<const float4*>(
                         src_h + (size_t)src_idx[e] * 256) + lane);
    float* dst = out + (size_t)dst_idx[e] * 256 + (size_t)lane * 4;
    unsafeAtomicAdd(dst + 0, v.x * w);
    unsafeAtomicAdd(dst + 1, v.y * w);
    unsafeAtomicAdd(dst + 2, v.z * w);
    unsafeAtomicAdd(dst + 3, v.w * w);
}

extern "C" void kernel_launch(void* const* d_in, const int* in_sizes, int n_in,
                              void* d_out, int out_size, void* d_ws, size_t ws_size,
                              hipStream_t stream)
{
    const float* paper_h  = (const float*)d_in[0];
    const float* author_h = (const float*)d_in[1];
    const int*   wb_src   = (const int*)d_in[2];
    const int*   wb_dst   = (const int*)d_in[3];
    const float* wb_w     = (const float*)d_in[4];
    const int*   pi_src   = (const int*)d_in[5];
    const int*   pi_dst   = (const int*)d_in[6];
    const float* pi_alpha = (const float*)d_in[7];
    const float* pi_w     = (const float*)d_in[8];
    const int*   hp_src   = (const int*)d_in[9];
    const int*   hp_dst   = (const int*)d_in[10];
    const float* hp_feat  = (const float*)d_in[11];
    const float* hp_alpha = (const float*)d_in[12];

    const int D = 256;
    const int n_paper  = in_sizes[0] / D;
    const int n_author = in_sizes[1] / D;
    const int E_wb = in_sizes[2];
    const int E_pi = in_sizes[5];
    const int E_hp = in_sizes[9];
    const int n_venue = out_size / D - n_paper - n_author;
    const int E_tot = E_wb + E_pi + E_hp;
    const int ncat  = n_author + 2 * n_venue;

    float* out        = (float*)d_out;
    float* out_paper  = out;
    float* out_author = out + (size_t)n_paper * D;
    float* out_venue  = out_author + (size_t)n_author * D;

    // ---- workspace layout ----
    int* W = (int*)d_ws;
    int*   counts   = W;                         // ncat
    int*   cursor   = counts + ncat;             // ncat
    int*   g        = cursor + ncat;             // ncat + 1 (global exclusive scan)
    int*   partials = g + ncat + 1;              // 4096
    int*   srcs_all = partials + 4096;           // E_tot
    float* ws_all   = (float*)(srcs_all + E_tot);// E_tot
    size_t need_bytes = (size_t)((int*)(ws_all + E_tot) - W) * sizeof(int);
    int nb = (ncat + 255) / 256;

    if (ws_size < need_bytes || nb > 4096) {
        // fallback: atomic scatter path
        hipMemsetAsync(out_author, 0,
                       ((size_t)n_author + n_venue) * D * sizeof(float), stream);
        hipMemcpyAsync(out_paper, paper_h, (size_t)n_paper * D * sizeof(float),
                       hipMemcpyDeviceToDevice, stream);
        auto launch = [&](const float* sh, const int* si, const int* di,
                          const float* w0, const float* w1, float* dst, int E) {
            if (E <= 0) return;
            edge_scatter_kernel<<<(E + 3) / 4, 256, 0, stream>>>(sh, si, di, w0, w1, dst, E);
        };
        launch(paper_h,  wb_src, wb_dst, wb_w,     nullptr,  out_author, E_wb);
        launch(paper_h,  pi_src, pi_dst, pi_alpha, pi_w,     out_venue,  E_pi);
        launch(author_h, hp_src, hp_dst, hp_feat,  hp_alpha, out_venue,  E_hp);
        return;
    }

    // zero counters+cursors (contiguous) and the venue accumulator region
    hipMemsetAsync(W, 0, (size_t)(2 * ncat) * sizeof(int), stream);
    hipMemsetAsync(out_venue, 0, (size_t)n_venue * D * sizeof(float), stream);

    // fused CSR build: 1 hist + 3 scan + 1 fill
    hist_all_kernel<<<(E_tot + 255) / 256, 256, 0, stream>>>(
        wb_dst, E_wb, pi_dst, E_pi, hp_dst, E_hp, n_author, n_venue, counts);
    scan_block_sums<<<nb, 256, 0, stream>>>(counts, ncat, partials);
    scan_partials_serial<<<1, 64, 0, stream>>>(partials, nb);
    scan_write_offs<<<nb, 256, 0, stream>>>(counts, ncat, partials, g);
    fill_all_kernel<<<(E_tot + 255) / 256, 256, 0, stream>>>(
        wb_dst, wb_src, wb_w, E_wb,
        pi_dst, pi_src, pi_alpha, pi_w, E_pi,
        hp_dst, hp_src, hp_feat, hp_alpha, E_hp,
        n_author, n_venue, g, cursor, srcs_all, ws_all);

    // paper passthrough (warms L3 with paper_h)
    hipMemcpyAsync(out_paper, paper_h, (size_t)n_paper * D * sizeof(float),
                   hipMemcpyDeviceToDevice, stream);

    // pi gather (reads paper_h while warm)
    constexpr int SPLIT = 4;
    gather_venue_part<SPLIT><<<((size_t)n_venue * SPLIT * 64 + 255) / 256, 256, 0, stream>>>(
        paper_h, g + n_author, srcs_all, ws_all, out_venue, n_venue);

    // author gather (reads paper_h, deg~3.3 reuse)
    gather_author_kernel<<<((size_t)n_author * 64 + 255) / 256, 256, 0, stream>>>(
        paper_h, g, srcs_all, ws_all, out_author, n_author);

    // hp gather last: working set = author_h (154 MB) fits L3
    gather_venue_part<SPLIT><<<((size_t)n_venue * SPLIT * 64 + 255) / 256, 256, 0, stream>>>(
        author_h, g + n_author + n_venue, srcs_all, ws_all, out_venue, n_venue);
}

// Round 6
// 754.684 us; speedup vs baseline: 1.2944x; 1.2944x over previous
//
#include <hip/hip_runtime.h>

// PropLayer: 3 weighted segment-sums + passthrough.
// Fused CSR build (concatenated counters, single scan) + ONE mega kernel doing
// copy + author gather + venue gather with deep MLP (unroll-8 masked loads).
// out layout (floats): [paper N_P*256][author N_A*256][venue N_V*256]
// counter layout:      [author 0..N_A) | pi N_A..N_A+N_V) | hp ..+N_V)

typedef float f32x4 __attribute__((ext_vector_type(4)));

// ---------------- fused CSR build ----------------

__global__ __launch_bounds__(256) void hist_all_kernel(
    const int* __restrict__ wb_dst, int E_wb,
    const int* __restrict__ pi_dst, int E_pi,
    const int* __restrict__ hp_dst, int E_hp,
    int n_author, int n_venue, int* __restrict__ counts)
{
    int e = blockIdx.x * blockDim.x + threadIdx.x;
    int idx;
    if (e < E_wb)                    idx = wb_dst[e];
    else if (e < E_wb + E_pi)        idx = n_author + pi_dst[e - E_wb];
    else if (e < E_wb + E_pi + E_hp) idx = n_author + n_venue + hp_dst[e - E_wb - E_pi];
    else return;
    atomicAdd(&counts[idx], 1);
}

__global__ __launch_bounds__(256) void scan_block_sums(const int* __restrict__ counts, int n,
                                                       int* __restrict__ partials) {
    __shared__ int s[256];
    int i = blockIdx.x * 256 + threadIdx.x;
    s[threadIdx.x] = (i < n) ? counts[i] : 0;
    __syncthreads();
    for (int st = 128; st > 0; st >>= 1) {
        if (threadIdx.x < st) s[threadIdx.x] += s[threadIdx.x + st];
        __syncthreads();
    }
    if (threadIdx.x == 0) partials[blockIdx.x] = s[0];
}

// single-block LDS scan of up to 1024 partials (replaces serial 1-thread scan)
__global__ __launch_bounds__(1024) void scan_partials_block(int* partials, int m) {
    __shared__ int s[1024];
    int i = threadIdx.x;
    int v = (i < m) ? partials[i] : 0;
    s[i] = v;
    __syncthreads();
    for (int st = 1; st < 1024; st <<= 1) {
        int t = (i >= st) ? s[i - st] : 0;
        __syncthreads();
        s[i] += t;
        __syncthreads();
    }
    if (i < m) partials[i] = s[i] - v;   // exclusive
}

__global__ __launch_bounds__(256) void scan_write_offs(const int* __restrict__ counts, int n,
                                                       const int* __restrict__ partials,
                                                       int* __restrict__ offs) {
    __shared__ int s[256];
    int i = blockIdx.x * 256 + threadIdx.x;
    int v = (i < n) ? counts[i] : 0;
    s[threadIdx.x] = v;
    __syncthreads();
    for (int st = 1; st < 256; st <<= 1) {
        int t = (threadIdx.x >= st) ? s[threadIdx.x - st] : 0;
        __syncthreads();
        s[threadIdx.x] += t;
        __syncthreads();
    }
    int incl = s[threadIdx.x];
    if (i < n) offs[i] = partials[blockIdx.x] + (incl - v);
    if (i == n - 1) offs[n] = partials[blockIdx.x] + incl;
}

// writes dst-sorted (src, combined-weight) at GLOBAL positions
__global__ __launch_bounds__(256) void fill_all_kernel(
    const int* __restrict__ wb_dst, const int* __restrict__ wb_src,
    const float* __restrict__ wb_w, int E_wb,
    const int* __restrict__ pi_dst, const int* __restrict__ pi_src,
    const float* __restrict__ pi_alpha, const float* __restrict__ pi_w, int E_pi,
    const int* __restrict__ hp_dst, const int* __restrict__ hp_src,
    const float* __restrict__ hp_feat, const float* __restrict__ hp_alpha, int E_hp,
    int n_author, int n_venue,
    const int* __restrict__ g, int* __restrict__ cursor,
    int* __restrict__ srcs_out, float* __restrict__ ws_out)
{
    int e = blockIdx.x * blockDim.x + threadIdx.x;
    int idx, src; float w;
    if (e < E_wb) {
        idx = wb_dst[e]; src = wb_src[e]; w = wb_w[e];
    } else if (e < E_wb + E_pi) {
        int i = e - E_wb;
        idx = n_author + pi_dst[i]; src = pi_src[i]; w = pi_alpha[i] * pi_w[i];
    } else if (e < E_wb + E_pi + E_hp) {
        int i = e - E_wb - E_pi;
        idx = n_author + n_venue + hp_dst[i]; src = hp_src[i]; w = hp_feat[i] * hp_alpha[i];
    } else return;
    int pos = g[idx] + atomicAdd(&cursor[idx], 1);
    srcs_out[pos] = src;
    ws_out[pos]   = w;
}

// ---------------- mega kernel: copy + author + venue ----------------

// accumulate rows [beg,end) with 8 loads always in flight (masked tail)
__device__ __forceinline__ void gather_rows(const float* __restrict__ h,
    const int* __restrict__ srcs, const float* __restrict__ ws,
    int beg, int end, int lane, f32x4& acc)
{
    for (int p = beg; p < end; p += 8) {
        int s[8]; float w[8];
        #pragma unroll
        for (int i = 0; i < 8; ++i) {
            int q = p + i;
            bool ok = q < end;
            s[i] = ok ? srcs[q] : srcs[beg];
            w[i] = ok ? ws[q]   : 0.f;
        }
        f32x4 v[8];
        #pragma unroll
        for (int i = 0; i < 8; ++i)
            v[i] = *(reinterpret_cast<const f32x4*>(h + (size_t)s[i] * 256) + lane);
        #pragma unroll
        for (int i = 0; i < 8; ++i)
            acc += v[i] * w[i];
    }
}

template<int SPLIT, int CPW>
__global__ __launch_bounds__(256) void fused_gather_copy_kernel(
    const float* __restrict__ paper_h, const float* __restrict__ author_h,
    const int* __restrict__ g,              // global offsets [ncat+1]
    const int* __restrict__ srcs_all, const float* __restrict__ ws_all,
    float* __restrict__ out_paper, float* __restrict__ out_author,
    float* __restrict__ out_venue,
    int n_paper, int n_author, int n_venue, int n_copy_waves)
{
    int wid  = (blockIdx.x * blockDim.x + threadIdx.x) >> 6;
    int lane = threadIdx.x & 63;
    const int nv_split = n_venue * SPLIT;

    if (wid < nv_split) {
        // ---- venue wave: row `row`, partition `part` over pi+hp edge lists
        int row = wid / SPLIT, part = wid % SPLIT;
        f32x4 acc = {0.f, 0.f, 0.f, 0.f};
        bool any = false;
        #pragma unroll
        for (int gph = 0; gph < 2; ++gph) {
            const int base = gph ? (n_author + n_venue) : n_author;
            const float* h = gph ? author_h : paper_h;
            int beg0 = g[base + row], end0 = g[base + row + 1];
            int total = end0 - beg0;
            int per = (total + SPLIT - 1) / SPLIT;
            int beg = beg0 + part * per;
            int end = min(beg + per, end0);
            if (beg < end) {
                any = true;
                gather_rows(h, srcs_all, ws_all, beg, end, lane, acc);
            }
        }
        if (any) {
            float* dst = out_venue + (size_t)row * 256 + (size_t)lane * 4;
            unsafeAtomicAdd(dst + 0, acc.x);
            unsafeAtomicAdd(dst + 1, acc.y);
            unsafeAtomicAdd(dst + 2, acc.z);
            unsafeAtomicAdd(dst + 3, acc.w);
        }
    } else if (wid < nv_split + n_author) {
        // ---- author wave: one output row, direct store
        int row = wid - nv_split;
        f32x4 acc = {0.f, 0.f, 0.f, 0.f};
        gather_rows(paper_h, srcs_all, ws_all, g[row], g[row + 1], lane, acc);
        *(reinterpret_cast<f32x4*>(out_author + (size_t)row * 256) + lane) = acc;
    } else if (wid < nv_split + n_author + n_copy_waves) {
        // ---- copy wave: CPW paper rows, nontemporal stores
        int j = wid - nv_split - n_author;
        int r0 = j * CPW;
        int r1 = min(r0 + CPW, n_paper);
        f32x4 v[CPW];
        #pragma unroll
        for (int i = 0; i < CPW; ++i)
            if (r0 + i < r1)
                v[i] = *(reinterpret_cast<const f32x4*>(paper_h + (size_t)(r0 + i) * 256) + lane);
        #pragma unroll
        for (int i = 0; i < CPW; ++i)
            if (r0 + i < r1)
                __builtin_nontemporal_store(v[i],
                    reinterpret_cast<f32x4*>(out_paper + (size_t)(r0 + i) * 256) + lane);
    }
}

// ---------------- fallback (atomic scatter path) ----------------

__global__ __launch_bounds__(256) void edge_scatter_kernel(
    const float* __restrict__ src_h, const int* __restrict__ src_idx,
    const int* __restrict__ dst_idx, const float* __restrict__ w0,
    const float* __restrict__ w1, float* __restrict__ out, int n_edges)
{
    int tid = blockIdx.x * blockDim.x + threadIdx.x;
    int e = tid >> 6;
    if (e >= n_edges) return;
    int lane = tid & 63;
    float w = w0[e];
    if (w1) w *= w1[e];
    const f32x4 v = *(reinterpret_cast<const f32x4*>(
                        src_h + (size_t)src_idx[e] * 256) + lane);
    float* dst = out + (size_t)dst_idx[e] * 256 + (size_t)lane * 4;
    unsafeAtomicAdd(dst + 0, v.x * w);
    unsafeAtomicAdd(dst + 1, v.y * w);
    unsafeAtomicAdd(dst + 2, v.z * w);
    unsafeAtomicAdd(dst + 3, v.w * w);
}

extern "C" void kernel_launch(void* const* d_in, const int* in_sizes, int n_in,
                              void* d_out, int out_size, void* d_ws, size_t ws_size,
                              hipStream_t stream)
{
    const float* paper_h  = (const float*)d_in[0];
    const float* author_h = (const float*)d_in[1];
    const int*   wb_src   = (const int*)d_in[2];
    const int*   wb_dst   = (const int*)d_in[3];
    const float* wb_w     = (const float*)d_in[4];
    const int*   pi_src   = (const int*)d_in[5];
    const int*   pi_dst   = (const int*)d_in[6];
    const float* pi_alpha = (const float*)d_in[7];
    const float* pi_w     = (const float*)d_in[8];
    const int*   hp_src   = (const int*)d_in[9];
    const int*   hp_dst   = (const int*)d_in[10];
    const float* hp_feat  = (const float*)d_in[11];
    const float* hp_alpha = (const float*)d_in[12];

    const int D = 256;
    const int n_paper  = in_sizes[0] / D;
    const int n_author = in_sizes[1] / D;
    const int E_wb = in_sizes[2];
    const int E_pi = in_sizes[5];
    const int E_hp = in_sizes[9];
    const int n_venue = out_size / D - n_paper - n_author;
    const int E_tot = E_wb + E_pi + E_hp;
    const int ncat  = n_author + 2 * n_venue;

    float* out        = (float*)d_out;
    float* out_paper  = out;
    float* out_author = out + (size_t)n_paper * D;
    float* out_venue  = out_author + (size_t)n_author * D;

    // ---- workspace layout ----
    int* W = (int*)d_ws;
    int*   counts   = W;                         // ncat
    int*   cursor   = counts + ncat;             // ncat
    int*   g        = cursor + ncat;             // ncat + 1
    int*   partials = g + ncat + 1;              // 1024
    int*   srcs_all = partials + 1024;           // E_tot
    float* ws_all   = (float*)(srcs_all + E_tot);// E_tot
    size_t need_bytes = (size_t)((int*)(ws_all + E_tot) - W) * sizeof(int);
    int nb = (ncat + 255) / 256;

    if (ws_size < need_bytes || nb > 1024) {
        // fallback: atomic scatter path
        hipMemsetAsync(out_author, 0,
                       ((size_t)n_author + n_venue) * D * sizeof(float), stream);
        hipMemcpyAsync(out_paper, paper_h, (size_t)n_paper * D * sizeof(float),
                       hipMemcpyDeviceToDevice, stream);
        auto launch = [&](const float* sh, const int* si, const int* di,
                          const float* w0, const float* w1, float* dst, int E) {
            if (E <= 0) return;
            edge_scatter_kernel<<<(E + 3) / 4, 256, 0, stream>>>(sh, si, di, w0, w1, dst, E);
        };
        launch(paper_h,  wb_src, wb_dst, wb_w,     nullptr,  out_author, E_wb);
        launch(paper_h,  pi_src, pi_dst, pi_alpha, pi_w,     out_venue,  E_pi);
        launch(author_h, hp_src, hp_dst, hp_feat,  hp_alpha, out_venue,  E_hp);
        return;
    }

    // zero counters+cursors (contiguous) and the venue accumulator region
    hipMemsetAsync(W, 0, (size_t)(2 * ncat) * sizeof(int), stream);
    hipMemsetAsync(out_venue, 0, (size_t)n_venue * D * sizeof(float), stream);

    // fused CSR build: hist + 3-phase scan + fill
    hist_all_kernel<<<(E_tot + 255) / 256, 256, 0, stream>>>(
        wb_dst, E_wb, pi_dst, E_pi, hp_dst, E_hp, n_author, n_venue, counts);
    scan_block_sums<<<nb, 256, 0, stream>>>(counts, ncat, partials);
    scan_partials_block<<<1, 1024, 0, stream>>>(partials, nb);
    scan_write_offs<<<nb, 256, 0, stream>>>(counts, ncat, partials, g);
    fill_all_kernel<<<(E_tot + 255) / 256, 256, 0, stream>>>(
        wb_dst, wb_src, wb_w, E_wb,
        pi_dst, pi_src, pi_alpha, pi_w, E_pi,
        hp_dst, hp_src, hp_feat, hp_alpha, E_hp,
        n_author, n_venue, g, cursor, srcs_all, ws_all);

    // mega kernel: venue gather + author gather + paper copy in one launch
    constexpr int SPLIT = 4;
    constexpr int CPW   = 4;
    const int n_copy_waves = (n_paper + CPW - 1) / CPW;
    const long long total_waves = (long long)n_venue * SPLIT + n_author + n_copy_waves;
    const long long total_threads = total_waves * 64;
    const int blocks = (int)((total_threads + 255) / 256);

    fused_gather_copy_kernel<SPLIT, CPW><<<blocks, 256, 0, stream>>>(
        paper_h, author_h, g, srcs_all, ws_all,
        out_paper, out_author, out_venue,
        n_paper, n_author, n_venue, n_copy_waves);
}

// Round 7
// 735.204 us; speedup vs baseline: 1.3287x; 1.0265x over previous
//
#include <hip/hip_runtime.h>

// PropLayer: 3 weighted segment-sums + passthrough.
// CSR-gather. Copy is co-scheduled with the latency-bound CSR-build kernels
// (hist, fill) via block partitioning; gather kernel carries only gathers.
// Metadata packed as int2 (src, weight-bits).
// out layout (floats): [paper N_P*256][author N_A*256][venue N_V*256]
// counter layout:      [author 0..N_A) | pi N_A..N_A+N_V) | hp ..+N_V)

typedef float f32x4 __attribute__((ext_vector_type(4)));

// ---------------- shared device helpers ----------------

template<int CPW>
__device__ __forceinline__ void copy_rows(const float* __restrict__ paper_h,
                                          float* __restrict__ out_paper,
                                          int j, int lane, int row0, int row1)
{
    int r0 = row0 + j * CPW;
    if (r0 >= row1) return;
    int r1 = min(r0 + CPW, row1);
    f32x4 v[CPW];
    #pragma unroll
    for (int i = 0; i < CPW; ++i)
        if (r0 + i < r1)
            v[i] = *(reinterpret_cast<const f32x4*>(paper_h + (size_t)(r0 + i) * 256) + lane);
    #pragma unroll
    for (int i = 0; i < CPW; ++i)
        if (r0 + i < r1)
            __builtin_nontemporal_store(v[i],
                reinterpret_cast<f32x4*>(out_paper + (size_t)(r0 + i) * 256) + lane);
}

// ---------------- K1: hist + copy part A ----------------

template<int CPW>
__global__ __launch_bounds__(256) void hist_copy_kernel(
    const int* __restrict__ wb_dst, int E_wb,
    const int* __restrict__ pi_dst, int E_pi,
    const int* __restrict__ hp_dst, int E_hp,
    int n_author, int n_venue, int* __restrict__ counts,
    const float* __restrict__ paper_h, float* __restrict__ out_paper,
    int copy_row0, int copy_row1, int hist_blocks)
{
    if ((int)blockIdx.x < hist_blocks) {
        int e = blockIdx.x * 256 + threadIdx.x;
        int idx;
        if (e < E_wb)                    idx = wb_dst[e];
        else if (e < E_wb + E_pi)        idx = n_author + pi_dst[e - E_wb];
        else if (e < E_wb + E_pi + E_hp) idx = n_author + n_venue + hp_dst[e - E_wb - E_pi];
        else return;
        atomicAdd(&counts[idx], 1);
    } else {
        int j = (int)(((blockIdx.x - hist_blocks) * 256 + threadIdx.x) >> 6);
        copy_rows<CPW>(paper_h, out_paper, j, threadIdx.x & 63, copy_row0, copy_row1);
    }
}

// ---------------- scan ----------------

__global__ __launch_bounds__(256) void scan_block_sums(const int* __restrict__ counts, int n,
                                                       int* __restrict__ partials) {
    __shared__ int s[256];
    int i = blockIdx.x * 256 + threadIdx.x;
    s[threadIdx.x] = (i < n) ? counts[i] : 0;
    __syncthreads();
    for (int st = 128; st > 0; st >>= 1) {
        if (threadIdx.x < st) s[threadIdx.x] += s[threadIdx.x + st];
        __syncthreads();
    }
    if (threadIdx.x == 0) partials[blockIdx.x] = s[0];
}

__global__ __launch_bounds__(1024) void scan_partials_block(int* partials, int m) {
    __shared__ int s[1024];
    int i = threadIdx.x;
    int v = (i < m) ? partials[i] : 0;
    s[i] = v;
    __syncthreads();
    for (int st = 1; st < 1024; st <<= 1) {
        int t = (i >= st) ? s[i - st] : 0;
        __syncthreads();
        s[i] += t;
        __syncthreads();
    }
    if (i < m) partials[i] = s[i] - v;   // exclusive
}

__global__ __launch_bounds__(256) void scan_write_offs(const int* __restrict__ counts, int n,
                                                       const int* __restrict__ partials,
                                                       int* __restrict__ offs) {
    __shared__ int s[256];
    int i = blockIdx.x * 256 + threadIdx.x;
    int v = (i < n) ? counts[i] : 0;
    s[threadIdx.x] = v;
    __syncthreads();
    for (int st = 1; st < 256; st <<= 1) {
        int t = (threadIdx.x >= st) ? s[threadIdx.x - st] : 0;
        __syncthreads();
        s[threadIdx.x] += t;
        __syncthreads();
    }
    int incl = s[threadIdx.x];
    if (i < n) offs[i] = partials[blockIdx.x] + (incl - v);
    if (i == n - 1) offs[n] = partials[blockIdx.x] + incl;
}

// ---------------- K3: fill (packed int2) + copy part B ----------------

template<int CPW>
__global__ __launch_bounds__(256) void fill_copy_kernel(
    const int* __restrict__ wb_dst, const int* __restrict__ wb_src,
    const float* __restrict__ wb_w, int E_wb,
    const int* __restrict__ pi_dst, const int* __restrict__ pi_src,
    const float* __restrict__ pi_alpha, const float* __restrict__ pi_w, int E_pi,
    const int* __restrict__ hp_dst, const int* __restrict__ hp_src,
    const float* __restrict__ hp_feat, const float* __restrict__ hp_alpha, int E_hp,
    int n_author, int n_venue,
    const int* __restrict__ g, int* __restrict__ cursor,
    int2* __restrict__ meta_out,
    const float* __restrict__ paper_h, float* __restrict__ out_paper,
    int copy_row0, int copy_row1, int fill_blocks)
{
    if ((int)blockIdx.x < fill_blocks) {
        int e = blockIdx.x * 256 + threadIdx.x;
        int idx, src; float w;
        if (e < E_wb) {
            idx = wb_dst[e]; src = wb_src[e]; w = wb_w[e];
        } else if (e < E_wb + E_pi) {
            int i = e - E_wb;
            idx = n_author + pi_dst[i]; src = pi_src[i]; w = pi_alpha[i] * pi_w[i];
        } else if (e < E_wb + E_pi + E_hp) {
            int i = e - E_wb - E_pi;
            idx = n_author + n_venue + hp_dst[i]; src = hp_src[i]; w = hp_feat[i] * hp_alpha[i];
        } else return;
        int pos = g[idx] + atomicAdd(&cursor[idx], 1);
        meta_out[pos] = make_int2(src, __float_as_int(w));
    } else {
        int j = (int)(((blockIdx.x - fill_blocks) * 256 + threadIdx.x) >> 6);
        copy_rows<CPW>(paper_h, out_paper, j, threadIdx.x & 63, copy_row0, copy_row1);
    }
}

// ---------------- K4: gather (venue split + author) ----------------

__device__ __forceinline__ void gather_rows(const float* __restrict__ h,
    const int2* __restrict__ meta, int beg, int end, int lane, f32x4& acc)
{
    for (int p = beg; p < end; p += 8) {
        int s[8]; float w[8];
        #pragma unroll
        for (int i = 0; i < 8; ++i) {
            int q = p + i;
            bool ok = q < end;
            int2 m = meta[ok ? q : beg];
            s[i] = m.x;
            w[i] = ok ? __int_as_float(m.y) : 0.f;
        }
        f32x4 v[8];
        #pragma unroll
        for (int i = 0; i < 8; ++i)
            v[i] = *(reinterpret_cast<const f32x4*>(h + (size_t)s[i] * 256) + lane);
        #pragma unroll
        for (int i = 0; i < 8; ++i)
            acc += v[i] * w[i];
    }
}

template<int SPLIT>
__global__ __launch_bounds__(256) void gather_kernel(
    const float* __restrict__ paper_h, const float* __restrict__ author_h,
    const int* __restrict__ g,              // global offsets [ncat+1]
    const int2* __restrict__ meta,
    float* __restrict__ out_author, float* __restrict__ out_venue,
    int n_author, int n_venue)
{
    int wid  = (int)((blockIdx.x * blockDim.x + threadIdx.x) >> 6);
    int lane = threadIdx.x & 63;
    const int nv_split = n_venue * SPLIT;

    if (wid < nv_split) {
        int row = wid / SPLIT, part = wid % SPLIT;
        f32x4 acc = {0.f, 0.f, 0.f, 0.f};
        bool any = false;
        #pragma unroll
        for (int gph = 0; gph < 2; ++gph) {
            const int base = gph ? (n_author + n_venue) : n_author;
            const float* h = gph ? author_h : paper_h;
            int beg0 = g[base + row], end0 = g[base + row + 1];
            int total = end0 - beg0;
            int per = (total + SPLIT - 1) / SPLIT;
            int beg = beg0 + part * per;
            int end = min(beg + per, end0);
            if (beg < end) {
                any = true;
                gather_rows(h, meta, beg, end, lane, acc);
            }
        }
        if (any) {
            float* dst = out_venue + (size_t)row * 256 + (size_t)lane * 4;
            unsafeAtomicAdd(dst + 0, acc.x);
            unsafeAtomicAdd(dst + 1, acc.y);
            unsafeAtomicAdd(dst + 2, acc.z);
            unsafeAtomicAdd(dst + 3, acc.w);
        }
    } else if (wid < nv_split + n_author) {
        int row = wid - nv_split;
        f32x4 acc = {0.f, 0.f, 0.f, 0.f};
        gather_rows(paper_h, meta, g[row], g[row + 1], lane, acc);
        *(reinterpret_cast<f32x4*>(out_author + (size_t)row * 256) + lane) = acc;
    }
}

// ---------------- fallback (atomic scatter path) ----------------

__global__ __launch_bounds__(256) void edge_scatter_kernel(
    const float* __restrict__ src_h, const int* __restrict__ src_idx,
    const int* __restrict__ dst_idx, const float* __restrict__ w0,
    const float* __restrict__ w1, float* __restrict__ out, int n_edges)
{
    int tid = blockIdx.x * blockDim.x + threadIdx.x;
    int e = tid >> 6;
    if (e >= n_edges) return;
    int lane = tid & 63;
    float w = w0[e];
    if (w1) w *= w1[e];
    const f32x4 v = *(reinterpret_cast<const f32x4*>(
                        src_h + (size_t)src_idx[e] * 256) + lane);
    float* dst = out + (size_t)dst_idx[e] * 256 + (size_t)lane * 4;
    unsafeAtomicAdd(dst + 0, v.x * w);
    unsafeAtomicAdd(dst + 1, v.y * w);
    unsafeAtomicAdd(dst + 2, v.z * w);
    unsafeAtomicAdd(dst + 3, v.w * w);
}

extern "C" void kernel_launch(void* const* d_in, const int* in_sizes, int n_in,
                              void* d_out, int out_size, void* d_ws, size_t ws_size,
                              hipStream_t stream)
{
    const float* paper_h  = (const float*)d_in[0];
    const float* author_h = (const float*)d_in[1];
    const int*   wb_src   = (const int*)d_in[2];
    const int*   wb_dst   = (const int*)d_in[3];
    const float* wb_w     = (const float*)d_in[4];
    const int*   pi_src   = (const int*)d_in[5];
    const int*   pi_dst   = (const int*)d_in[6];
    const float* pi_alpha = (const float*)d_in[7];
    const float* pi_w     = (const float*)d_in[8];
    const int*   hp_src   = (const int*)d_in[9];
    const int*   hp_dst   = (const int*)d_in[10];
    const float* hp_feat  = (const float*)d_in[11];
    const float* hp_alpha = (const float*)d_in[12];

    const int D = 256;
    const int n_paper  = in_sizes[0] / D;
    const int n_author = in_sizes[1] / D;
    const int E_wb = in_sizes[2];
    const int E_pi = in_sizes[5];
    const int E_hp = in_sizes[9];
    const int n_venue = out_size / D - n_paper - n_author;
    const int E_tot = E_wb + E_pi + E_hp;
    const int ncat  = n_author + 2 * n_venue;

    float* out        = (float*)d_out;
    float* out_paper  = out;
    float* out_author = out + (size_t)n_paper * D;
    float* out_venue  = out_author + (size_t)n_author * D;

    // ---- workspace layout ----
    int* W = (int*)d_ws;
    int*   counts   = W;                         // ncat
    int*   cursor   = counts + ncat;             // ncat
    int*   g        = cursor + ncat;             // ncat + 1
    int*   partials = g + ncat + 1;              // 1024
    size_t meta_off = (size_t)(partials + 1024 - W);
    meta_off = (meta_off + 1) & ~(size_t)1;      // 8B-align
    int2*  meta     = (int2*)(W + meta_off);     // E_tot int2
    size_t need_bytes = (meta_off + 2 * (size_t)E_tot) * sizeof(int);
    int nb = (ncat + 255) / 256;

    if (ws_size < need_bytes || nb > 1024) {
        // fallback: atomic scatter path
        hipMemsetAsync(out_author, 0,
                       ((size_t)n_author + n_venue) * D * sizeof(float), stream);
        hipMemcpyAsync(out_paper, paper_h, (size_t)n_paper * D * sizeof(float),
                       hipMemcpyDeviceToDevice, stream);
        auto launch = [&](const float* sh, const int* si, const int* di,
                          const float* w0, const float* w1, float* dst, int E) {
            if (E <= 0) return;
            edge_scatter_kernel<<<(E + 3) / 4, 256, 0, stream>>>(sh, si, di, w0, w1, dst, E);
        };
        launch(paper_h,  wb_src, wb_dst, wb_w,     nullptr,  out_author, E_wb);
        launch(paper_h,  pi_src, pi_dst, pi_alpha, pi_w,     out_venue,  E_pi);
        launch(author_h, hp_src, hp_dst, hp_feat,  hp_alpha, out_venue,  E_hp);
        return;
    }

    // zero counters+cursors (contiguous) and the venue accumulator region
    hipMemsetAsync(W, 0, (size_t)(2 * ncat) * sizeof(int), stream);
    hipMemsetAsync(out_venue, 0, (size_t)n_venue * D * sizeof(float), stream);

    constexpr int CPW = 4;

    // split copy rows between K1 (hist) and K3 (fill): fill is pricier, give it less
    const int rowsA_end = n_paper / 2;

    // K1: hist + copy part A
    {
        const int hist_blocks = (E_tot + 255) / 256;
        const int copy_waves  = (rowsA_end + CPW - 1) / CPW;
        const int copy_blocks = (copy_waves * 64 + 255) / 256;
        hist_copy_kernel<CPW><<<hist_blocks + copy_blocks, 256, 0, stream>>>(
            wb_dst, E_wb, pi_dst, E_pi, hp_dst, E_hp, n_author, n_venue, counts,
            paper_h, out_paper, 0, rowsA_end, hist_blocks);
    }

    // K2: scan
    scan_block_sums<<<nb, 256, 0, stream>>>(counts, ncat, partials);
    scan_partials_block<<<1, 1024, 0, stream>>>(partials, nb);
    scan_write_offs<<<nb, 256, 0, stream>>>(counts, ncat, partials, g);

    // K3: fill + copy part B
    {
        const int fill_blocks = (E_tot + 255) / 256;
        const int rowsB = n_paper - rowsA_end;
        const int copy_waves  = (rowsB + CPW - 1) / CPW;
        const int copy_blocks = (copy_waves * 64 + 255) / 256;
        fill_copy_kernel<CPW><<<fill_blocks + copy_blocks, 256, 0, stream>>>(
            wb_dst, wb_src, wb_w, E_wb,
            pi_dst, pi_src, pi_alpha, pi_w, E_pi,
            hp_dst, hp_src, hp_feat, hp_alpha, E_hp,
            n_author, n_venue, g, cursor, meta,
            paper_h, out_paper, rowsA_end, n_paper, fill_blocks);
    }

    // K4: gather
    constexpr int SPLIT = 4;
    const long long total_waves = (long long)n_venue * SPLIT + n_author;
    const int blocks = (int)((total_waves * 64 + 255) / 256);
    gather_kernel<SPLIT><<<blocks, 256, 0, stream>>>(
        paper_h, author_h, g, meta, out_author, out_venue, n_author, n_venue);
}

// Round 8
// 639.357 us; speedup vs baseline: 1.5278x; 1.1499x over previous
//
#include <hip/hip_runtime.h>

// PropLayer: 3 weighted segment-sums + passthrough.
// Bucketed-CSR (fixed caps, one atomic pass, no hist/scan) + copy co-scheduled
// with the bucket fill; gather kernel unchanged structure (unroll-8 MLP).
// out layout (floats): [paper N_P*256][author N_A*256][venue N_V*256]
// counter layout:      [author 0..N_A) | pi N_A..+N_V) | hp ..+N_V)

typedef float f32x4 __attribute__((ext_vector_type(4)));

constexpr int ACAP  = 32;   // author bucket capacity (mean deg 6.7, 9sigma+)
constexpr int PCAP  = 64;   // pi-venue bucket capacity (mean 30)
constexpr int HCAP  = 192;  // hp-venue bucket capacity (mean 100)
constexpr int SPLIT = 4;    // waves per venue row
constexpr int CPW   = 4;    // copy rows per wave

// ---------------- copy helper ----------------

__device__ __forceinline__ void copy_rows(const float* __restrict__ paper_h,
                                          float* __restrict__ out_paper,
                                          int j, int lane, int n_paper)
{
    int r0 = j * CPW;
    if (r0 >= n_paper) return;
    int r1 = min(r0 + CPW, n_paper);
    f32x4 v[CPW];
    #pragma unroll
    for (int i = 0; i < CPW; ++i)
        if (r0 + i < r1)
            v[i] = *(reinterpret_cast<const f32x4*>(paper_h + (size_t)(r0 + i) * 256) + lane);
    #pragma unroll
    for (int i = 0; i < CPW; ++i)
        if (r0 + i < r1)
            __builtin_nontemporal_store(v[i],
                reinterpret_cast<f32x4*>(out_paper + (size_t)(r0 + i) * 256) + lane);
}

// ---------------- K1: bucket fill + full copy ----------------
// copy blocks dispatched FIRST (streaming starts immediately); fill blocks after.

__global__ __launch_bounds__(256) void fill_copy_kernel(
    const int* __restrict__ wb_dst, const int* __restrict__ wb_src,
    const float* __restrict__ wb_w, int E_wb,
    const int* __restrict__ pi_dst, const int* __restrict__ pi_src,
    const float* __restrict__ pi_alpha, const float* __restrict__ pi_w, int E_pi,
    const int* __restrict__ hp_dst, const int* __restrict__ hp_src,
    const float* __restrict__ hp_feat, const float* __restrict__ hp_alpha, int E_hp,
    int n_author, int n_venue,
    int* __restrict__ cnts,               // [ncat]: author | pi | hp
    int2* __restrict__ ameta, int2* __restrict__ pmeta, int2* __restrict__ hmeta,
    int* __restrict__ ovf_cnt, int4* __restrict__ ovf,
    const float* __restrict__ paper_h, float* __restrict__ out_paper,
    int n_paper, int copy_blocks)
{
    if ((int)blockIdx.x < copy_blocks) {
        int j = (int)((blockIdx.x * 256 + threadIdx.x) >> 6);
        copy_rows(paper_h, out_paper, j, threadIdx.x & 63, n_paper);
        return;
    }
    int e = (blockIdx.x - copy_blocks) * 256 + threadIdx.x;
    int gidx, row, src, cap; float w; int2* meta;
    if (e < E_wb) {
        row = wb_dst[e]; gidx = row; src = wb_src[e]; w = wb_w[e];
        meta = ameta; cap = ACAP;
    } else if (e < E_wb + E_pi) {
        int i = e - E_wb;
        row = pi_dst[i]; gidx = n_author + row; src = pi_src[i];
        w = pi_alpha[i] * pi_w[i];
        meta = pmeta; cap = PCAP;
    } else if (e < E_wb + E_pi + E_hp) {
        int i = e - E_wb - E_pi;
        row = hp_dst[i]; gidx = n_author + n_venue + row; src = hp_src[i];
        w = hp_feat[i] * hp_alpha[i];
        meta = hmeta; cap = HCAP;
    } else return;

    int pos = atomicAdd(&cnts[gidx], 1);
    if (pos < cap) {
        meta[(size_t)row * cap + pos] = make_int2(src, __float_as_int(w));
    } else {
        int op = atomicAdd(ovf_cnt, 1);
        ovf[op] = make_int4(src, gidx, __float_as_int(w), 0);
    }
}

// ---------------- K2: gather (venue split + author) ----------------

__device__ __forceinline__ void gather_rows(const float* __restrict__ h,
    const int2* __restrict__ meta, int beg, int end, int lane, f32x4& acc)
{
    for (int p = beg; p < end; p += 8) {
        int s[8]; float w[8];
        #pragma unroll
        for (int i = 0; i < 8; ++i) {
            int q = p + i;
            bool ok = q < end;
            int2 m = meta[ok ? q : beg];
            s[i] = m.x;
            w[i] = ok ? __int_as_float(m.y) : 0.f;
        }
        f32x4 v[8];
        #pragma unroll
        for (int i = 0; i < 8; ++i)
            v[i] = *(reinterpret_cast<const f32x4*>(h + (size_t)s[i] * 256) + lane);
        #pragma unroll
        for (int i = 0; i < 8; ++i)
            acc += v[i] * w[i];
    }
}

__global__ __launch_bounds__(256) void gather_kernel(
    const float* __restrict__ paper_h, const float* __restrict__ author_h,
    const int* __restrict__ cnts,
    const int2* __restrict__ ameta, const int2* __restrict__ pmeta,
    const int2* __restrict__ hmeta,
    float* __restrict__ out_author, float* __restrict__ out_venue,
    int n_author, int n_venue)
{
    int wid  = (int)((blockIdx.x * blockDim.x + threadIdx.x) >> 6);
    int lane = threadIdx.x & 63;
    const int nv_split = n_venue * SPLIT;

    if (wid < nv_split) {
        int row = wid / SPLIT, part = wid % SPLIT;
        f32x4 acc = {0.f, 0.f, 0.f, 0.f};
        bool any = false;
        // pi part (paper_h)
        {
            int cnt = min(cnts[n_author + row], PCAP);
            int per = (cnt + SPLIT - 1) / SPLIT;
            int beg = part * per, end = min(beg + per, cnt);
            if (beg < end) {
                any = true;
                gather_rows(paper_h, pmeta + (size_t)row * PCAP, beg, end, lane, acc);
            }
        }
        // hp part (author_h)
        {
            int cnt = min(cnts[n_author + n_venue + row], HCAP);
            int per = (cnt + SPLIT - 1) / SPLIT;
            int beg = part * per, end = min(beg + per, cnt);
            if (beg < end) {
                any = true;
                gather_rows(author_h, hmeta + (size_t)row * HCAP, beg, end, lane, acc);
            }
        }
        if (any) {
            float* dst = out_venue + (size_t)row * 256 + (size_t)lane * 4;
            unsafeAtomicAdd(dst + 0, acc.x);
            unsafeAtomicAdd(dst + 1, acc.y);
            unsafeAtomicAdd(dst + 2, acc.z);
            unsafeAtomicAdd(dst + 3, acc.w);
        }
    } else if (wid < nv_split + n_author) {
        int row = wid - nv_split;
        f32x4 acc = {0.f, 0.f, 0.f, 0.f};
        int cnt = min(cnts[row], ACAP);
        gather_rows(paper_h, ameta + (size_t)row * ACAP, 0, cnt, lane, acc);
        __builtin_nontemporal_store(acc,
            reinterpret_cast<f32x4*>(out_author + (size_t)row * 256) + lane);
    }
}

// ---------------- K3: overflow scatter (normally empty) ----------------

__global__ __launch_bounds__(256) void ovf_scatter_kernel(
    const int* __restrict__ ovf_cnt, const int4* __restrict__ ovf,
    const float* __restrict__ paper_h, const float* __restrict__ author_h,
    float* __restrict__ out_author, float* __restrict__ out_venue,
    int n_author, int n_venue)
{
    int n = *ovf_cnt;
    if (n <= 0) return;
    int nw   = (int)((gridDim.x * blockDim.x) >> 6);
    int wid  = (int)((blockIdx.x * blockDim.x + threadIdx.x) >> 6);
    int lane = threadIdx.x & 63;
    for (int i = wid; i < n; i += nw) {
        int4 t = ovf[i];
        const float* h; float* dst;
        if (t.y < n_author)                { h = paper_h;  dst = out_author + (size_t)t.y * 256; }
        else if (t.y < n_author + n_venue) { h = paper_h;  dst = out_venue + (size_t)(t.y - n_author) * 256; }
        else                               { h = author_h; dst = out_venue + (size_t)(t.y - n_author - n_venue) * 256; }
        float w = __int_as_float(t.z);
        f32x4 v = *(reinterpret_cast<const f32x4*>(h + (size_t)t.x * 256) + lane);
        float* d = dst + (size_t)lane * 4;
        unsafeAtomicAdd(d + 0, v.x * w);
        unsafeAtomicAdd(d + 1, v.y * w);
        unsafeAtomicAdd(d + 2, v.z * w);
        unsafeAtomicAdd(d + 3, v.w * w);
    }
}

// ---------------- fallback (atomic scatter path) ----------------

__global__ __launch_bounds__(256) void edge_scatter_kernel(
    const float* __restrict__ src_h, const int* __restrict__ src_idx,
    const int* __restrict__ dst_idx, const float* __restrict__ w0,
    const float* __restrict__ w1, float* __restrict__ out, int n_edges)
{
    int tid = blockIdx.x * blockDim.x + threadIdx.x;
    int e = tid >> 6;
    if (e >= n_edges) return;
    int lane = tid & 63;
    float w = w0[e];
    if (w1) w *= w1[e];
    const f32x4 v = *(reinterpret_cast<const f32x4*>(
                        src_h + (size_t)src_idx[e] * 256) + lane);
    float* dst = out + (size_t)dst_idx[e] * 256 + (size_t)lane * 4;
    unsafeAtomicAdd(dst + 0, v.x * w);
    unsafeAtomicAdd(dst + 1, v.y * w);
    unsafeAtomicAdd(dst + 2, v.z * w);
    unsafeAtomicAdd(dst + 3, v.w * w);
}

extern "C" void kernel_launch(void* const* d_in, const int* in_sizes, int n_in,
                              void* d_out, int out_size, void* d_ws, size_t ws_size,
                              hipStream_t stream)
{
    const float* paper_h  = (const float*)d_in[0];
    const float* author_h = (const float*)d_in[1];
    const int*   wb_src   = (const int*)d_in[2];
    const int*   wb_dst   = (const int*)d_in[3];
    const float* wb_w     = (const float*)d_in[4];
    const int*   pi_src   = (const int*)d_in[5];
    const int*   pi_dst   = (const int*)d_in[6];
    const float* pi_alpha = (const float*)d_in[7];
    const float* pi_w     = (const float*)d_in[8];
    const int*   hp_src   = (const int*)d_in[9];
    const int*   hp_dst   = (const int*)d_in[10];
    const float* hp_feat  = (const float*)d_in[11];
    const float* hp_alpha = (const float*)d_in[12];

    const int D = 256;
    const int n_paper  = in_sizes[0] / D;
    const int n_author = in_sizes[1] / D;
    const int E_wb = in_sizes[2];
    const int E_pi = in_sizes[5];
    const int E_hp = in_sizes[9];
    const int n_venue = out_size / D - n_paper - n_author;
    const int E_tot = E_wb + E_pi + E_hp;
    const int ncat  = n_author + 2 * n_venue;

    float* out        = (float*)d_out;
    float* out_paper  = out;
    float* out_author = out + (size_t)n_paper * D;
    float* out_venue  = out_author + (size_t)n_author * D;

    // ---- workspace layout (16B-aligned sections) ----
    auto align16 = [](size_t b) { return (b + 15) & ~(size_t)15; };
    char* base = (char*)d_ws;
    size_t off = 0;
    int*  cnts    = (int*)(base + off);  off += (size_t)ncat * 4;
    int*  ovf_cnt = (int*)(base + off);  off += 4;           // contiguous with cnts for one memset
    size_t zero_bytes = off;
    off = align16(off);
    int4* ovf     = (int4*)(base + off); off += (size_t)E_tot * 16;
    int2* ameta   = (int2*)(base + off); off += (size_t)n_author * ACAP * 8;
    int2* pmeta   = (int2*)(base + off); off += (size_t)n_venue * PCAP * 8;
    int2* hmeta   = (int2*)(base + off); off += (size_t)n_venue * HCAP * 8;
    size_t need_bytes = off;

    if (ws_size < need_bytes) {
        // fallback: atomic scatter path
        hipMemsetAsync(out_author, 0,
                       ((size_t)n_author + n_venue) * D * sizeof(float), stream);
        hipMemcpyAsync(out_paper, paper_h, (size_t)n_paper * D * sizeof(float),
                       hipMemcpyDeviceToDevice, stream);
        auto launch = [&](const float* sh, const int* si, const int* di,
                          const float* w0, const float* w1, float* dst, int E) {
            if (E <= 0) return;
            edge_scatter_kernel<<<(E + 3) / 4, 256, 0, stream>>>(sh, si, di, w0, w1, dst, E);
        };
        launch(paper_h,  wb_src, wb_dst, wb_w,     nullptr,  out_author, E_wb);
        launch(paper_h,  pi_src, pi_dst, pi_alpha, pi_w,     out_venue,  E_pi);
        launch(author_h, hp_src, hp_dst, hp_feat,  hp_alpha, out_venue,  E_hp);
        return;
    }

    // zero cursors + overflow count, and the venue accumulator region
    hipMemsetAsync(cnts, 0, zero_bytes, stream);
    hipMemsetAsync(out_venue, 0, (size_t)n_venue * D * sizeof(float), stream);

    // K1: full copy (blocks first) + bucket fill
    {
        const int copy_waves  = (n_paper + CPW - 1) / CPW;
        const int copy_blocks = (copy_waves * 64 + 255) / 256;
        const int fill_blocks = (E_tot + 255) / 256;
        fill_copy_kernel<<<copy_blocks + fill_blocks, 256, 0, stream>>>(
            wb_dst, wb_src, wb_w, E_wb,
            pi_dst, pi_src, pi_alpha, pi_w, E_pi,
            hp_dst, hp_src, hp_feat, hp_alpha, E_hp,
            n_author, n_venue, cnts, ameta, pmeta, hmeta, ovf_cnt, ovf,
            paper_h, out_paper, n_paper, copy_blocks);
    }

    // K2: gather
    {
        const long long total_waves = (long long)n_venue * SPLIT + n_author;
        const int blocks = (int)((total_waves * 64 + 255) / 256);
        gather_kernel<<<blocks, 256, 0, stream>>>(
            paper_h, author_h, cnts, ameta, pmeta, hmeta,
            out_author, out_venue, n_author, n_venue);
    }

    // K3: overflow tail (normally zero work)
    ovf_scatter_kernel<<<64, 256, 0, stream>>>(
        ovf_cnt, ovf, paper_h, author_h, out_author, out_venue, n_author, n_venue);
}

// Round 9
// 582.022 us; speedup vs baseline: 1.6784x; 1.0985x over previous
//
#include <hip/hip_runtime.h>

// PropLayer: 3 weighted segment-sums + passthrough.
// Bucketed-CSR (fixed caps, one atomic pass) + copy co-scheduled with fill.
// Gather: one wave per venue row (pi then hp, plain nt store, no atomics,
// no venue memset), venue waves first; author waves backfill.
// out layout (floats): [paper N_P*256][author N_A*256][venue N_V*256]
// counter layout:      [author 0..N_A) | pi N_A..+N_V) | hp ..+N_V)

typedef float f32x4 __attribute__((ext_vector_type(4)));

constexpr int ACAP  = 32;   // author bucket capacity (mean deg 6.7)
constexpr int PCAP  = 64;   // pi-venue bucket capacity (mean 30)
constexpr int HCAP  = 192;  // hp-venue bucket capacity (mean 100)
constexpr int CPW   = 4;    // copy rows per wave

// ---------------- copy helper ----------------

__device__ __forceinline__ void copy_rows(const float* __restrict__ paper_h,
                                          float* __restrict__ out_paper,
                                          int j, int lane, int n_paper)
{
    int r0 = j * CPW;
    if (r0 >= n_paper) return;
    int r1 = min(r0 + CPW, n_paper);
    f32x4 v[CPW];
    #pragma unroll
    for (int i = 0; i < CPW; ++i)
        if (r0 + i < r1)
            v[i] = *(reinterpret_cast<const f32x4*>(paper_h + (size_t)(r0 + i) * 256) + lane);
    #pragma unroll
    for (int i = 0; i < CPW; ++i)
        if (r0 + i < r1)
            __builtin_nontemporal_store(v[i],
                reinterpret_cast<f32x4*>(out_paper + (size_t)(r0 + i) * 256) + lane);
}

// ---------------- K1: bucket fill + full copy ----------------

__global__ __launch_bounds__(256) void fill_copy_kernel(
    const int* __restrict__ wb_dst, const int* __restrict__ wb_src,
    const float* __restrict__ wb_w, int E_wb,
    const int* __restrict__ pi_dst, const int* __restrict__ pi_src,
    const float* __restrict__ pi_alpha, const float* __restrict__ pi_w, int E_pi,
    const int* __restrict__ hp_dst, const int* __restrict__ hp_src,
    const float* __restrict__ hp_feat, const float* __restrict__ hp_alpha, int E_hp,
    int n_author, int n_venue,
    int* __restrict__ cnts,               // [ncat]: author | pi | hp
    int2* __restrict__ ameta, int2* __restrict__ pmeta, int2* __restrict__ hmeta,
    int* __restrict__ ovf_cnt, int4* __restrict__ ovf,
    const float* __restrict__ paper_h, float* __restrict__ out_paper,
    int n_paper, int copy_blocks)
{
    if ((int)blockIdx.x < copy_blocks) {
        int j = (int)((blockIdx.x * 256 + threadIdx.x) >> 6);
        copy_rows(paper_h, out_paper, j, threadIdx.x & 63, n_paper);
        return;
    }
    int e = (blockIdx.x - copy_blocks) * 256 + threadIdx.x;
    int gidx, row, src, cap; float w; int2* meta;
    if (e < E_wb) {
        row = wb_dst[e]; gidx = row; src = wb_src[e]; w = wb_w[e];
        meta = ameta; cap = ACAP;
    } else if (e < E_wb + E_pi) {
        int i = e - E_wb;
        row = pi_dst[i]; gidx = n_author + row; src = pi_src[i];
        w = pi_alpha[i] * pi_w[i];
        meta = pmeta; cap = PCAP;
    } else if (e < E_wb + E_pi + E_hp) {
        int i = e - E_wb - E_pi;
        row = hp_dst[i]; gidx = n_author + n_venue + row; src = hp_src[i];
        w = hp_feat[i] * hp_alpha[i];
        meta = hmeta; cap = HCAP;
    } else return;

    int pos = atomicAdd(&cnts[gidx], 1);
    if (pos < cap) {
        meta[(size_t)row * cap + pos] = make_int2(src, __float_as_int(w));
    } else {
        int op = atomicAdd(ovf_cnt, 1);
        ovf[op] = make_int4(src, gidx, __float_as_int(w), 0);
    }
}

// ---------------- K2: gather (venue waves first, then author) ----------------

__device__ __forceinline__ void gather_rows(const float* __restrict__ h,
    const int2* __restrict__ meta, int beg, int end, int lane, f32x4& acc)
{
    for (int p = beg; p < end; p += 8) {
        int s[8]; float w[8];
        #pragma unroll
        for (int i = 0; i < 8; ++i) {
            int q = p + i;
            bool ok = q < end;
            int2 m = meta[ok ? q : beg];
            s[i] = m.x;
            w[i] = ok ? __int_as_float(m.y) : 0.f;
        }
        f32x4 v[8];
        #pragma unroll
        for (int i = 0; i < 8; ++i)
            v[i] = *(reinterpret_cast<const f32x4*>(h + (size_t)s[i] * 256) + lane);
        #pragma unroll
        for (int i = 0; i < 8; ++i)
            acc += v[i] * w[i];
    }
}

__global__ __launch_bounds__(256) void gather_kernel(
    const float* __restrict__ paper_h, const float* __restrict__ author_h,
    const int* __restrict__ cnts,
    const int2* __restrict__ ameta, const int2* __restrict__ pmeta,
    const int2* __restrict__ hmeta,
    float* __restrict__ out_author, float* __restrict__ out_venue,
    int n_author, int n_venue)
{
    int wid  = (int)((blockIdx.x * blockDim.x + threadIdx.x) >> 6);
    int lane = threadIdx.x & 63;

    if (wid < n_venue) {
        // one wave per venue row: pi (paper_h) then hp (author_h), single store
        int row = wid;
        f32x4 acc = {0.f, 0.f, 0.f, 0.f};
        {
            int cnt = min(cnts[n_author + row], PCAP);
            gather_rows(paper_h, pmeta + (size_t)row * PCAP, 0, cnt, lane, acc);
        }
        {
            int cnt = min(cnts[n_author + n_venue + row], HCAP);
            gather_rows(author_h, hmeta + (size_t)row * HCAP, 0, cnt, lane, acc);
        }
        __builtin_nontemporal_store(acc,
            reinterpret_cast<f32x4*>(out_venue + (size_t)row * 256) + lane);
    } else if (wid < n_venue + n_author) {
        int row = wid - n_venue;
        f32x4 acc = {0.f, 0.f, 0.f, 0.f};
        int cnt = min(cnts[row], ACAP);
        gather_rows(paper_h, ameta + (size_t)row * ACAP, 0, cnt, lane, acc);
        __builtin_nontemporal_store(acc,
            reinterpret_cast<f32x4*>(out_author + (size_t)row * 256) + lane);
    }
}

// ---------------- K3: overflow scatter (normally empty) ----------------

__global__ __launch_bounds__(256) void ovf_scatter_kernel(
    const int* __restrict__ ovf_cnt, const int4* __restrict__ ovf,
    const float* __restrict__ paper_h, const float* __restrict__ author_h,
    float* __restrict__ out_author, float* __restrict__ out_venue,
    int n_author, int n_venue)
{
    int n = *ovf_cnt;
    if (n <= 0) return;
    int nw   = (int)((gridDim.x * blockDim.x) >> 6);
    int wid  = (int)((blockIdx.x * blockDim.x + threadIdx.x) >> 6);
    int lane = threadIdx.x & 63;
    for (int i = wid; i < n; i += nw) {
        int4 t = ovf[i];
        const float* h; float* dst;
        if (t.y < n_author)                { h = paper_h;  dst = out_author + (size_t)t.y * 256; }
        else if (t.y < n_author + n_venue) { h = paper_h;  dst = out_venue + (size_t)(t.y - n_author) * 256; }
        else                               { h = author_h; dst = out_venue + (size_t)(t.y - n_author - n_venue) * 256; }
        float w = __int_as_float(t.z);
        f32x4 v = *(reinterpret_cast<const f32x4*>(h + (size_t)t.x * 256) + lane);
        float* d = dst + (size_t)lane * 4;
        unsafeAtomicAdd(d + 0, v.x * w);
        unsafeAtomicAdd(d + 1, v.y * w);
        unsafeAtomicAdd(d + 2, v.z * w);
        unsafeAtomicAdd(d + 3, v.w * w);
    }
}

// ---------------- fallback (atomic scatter path) ----------------

__global__ __launch_bounds__(256) void edge_scatter_kernel(
    const float* __restrict__ src_h, const int* __restrict__ src_idx,
    const int* __restrict__ dst_idx, const float* __restrict__ w0,
    const float* __restrict__ w1, float* __restrict__ out, int n_edges)
{
    int tid = blockIdx.x * blockDim.x + threadIdx.x;
    int e = tid >> 6;
    if (e >= n_edges) return;
    int lane = tid & 63;
    float w = w0[e];
    if (w1) w *= w1[e];
    const f32x4 v = *(reinterpret_cast<const f32x4*>(
                        src_h + (size_t)src_idx[e] * 256) + lane);
    float* dst = out + (size_t)dst_idx[e] * 256 + (size_t)lane * 4;
    unsafeAtomicAdd(dst + 0, v.x * w);
    unsafeAtomicAdd(dst + 1, v.y * w);
    unsafeAtomicAdd(dst + 2, v.z * w);
    unsafeAtomicAdd(dst + 3, v.w * w);
}

extern "C" void kernel_launch(void* const* d_in, const int* in_sizes, int n_in,
                              void* d_out, int out_size, void* d_ws, size_t ws_size,
                              hipStream_t stream)
{
    const float* paper_h  = (const float*)d_in[0];
    const float* author_h = (const float*)d_in[1];
    const int*   wb_src   = (const int*)d_in[2];
    const int*   wb_dst   = (const int*)d_in[3];
    const float* wb_w     = (const float*)d_in[4];
    const int*   pi_src   = (const int*)d_in[5];
    const int*   pi_dst   = (const int*)d_in[6];
    const float* pi_alpha = (const float*)d_in[7];
    const float* pi_w     = (const float*)d_in[8];
    const int*   hp_src   = (const int*)d_in[9];
    const int*   hp_dst   = (const int*)d_in[10];
    const float* hp_feat  = (const float*)d_in[11];
    const float* hp_alpha = (const float*)d_in[12];

    const int D = 256;
    const int n_paper  = in_sizes[0] / D;
    const int n_author = in_sizes[1] / D;
    const int E_wb = in_sizes[2];
    const int E_pi = in_sizes[5];
    const int E_hp = in_sizes[9];
    const int n_venue = out_size / D - n_paper - n_author;
    const int E_tot = E_wb + E_pi + E_hp;
    const int ncat  = n_author + 2 * n_venue;

    float* out        = (float*)d_out;
    float* out_paper  = out;
    float* out_author = out + (size_t)n_paper * D;
    float* out_venue  = out_author + (size_t)n_author * D;

    // ---- workspace layout (16B-aligned sections) ----
    auto align16 = [](size_t b) { return (b + 15) & ~(size_t)15; };
    char* base = (char*)d_ws;
    size_t off = 0;
    int*  cnts    = (int*)(base + off);  off += (size_t)ncat * 4;
    int*  ovf_cnt = (int*)(base + off);  off += 4;           // contiguous with cnts: one memset
    size_t zero_bytes = off;
    off = align16(off);
    int4* ovf     = (int4*)(base + off); off += (size_t)E_tot * 16;
    int2* ameta   = (int2*)(base + off); off += (size_t)n_author * ACAP * 8;
    int2* pmeta   = (int2*)(base + off); off += (size_t)n_venue * PCAP * 8;
    int2* hmeta   = (int2*)(base + off); off += (size_t)n_venue * HCAP * 8;
    size_t need_bytes = off;

    if (ws_size < need_bytes) {
        // fallback: atomic scatter path
        hipMemsetAsync(out_author, 0,
                       ((size_t)n_author + n_venue) * D * sizeof(float), stream);
        hipMemcpyAsync(out_paper, paper_h, (size_t)n_paper * D * sizeof(float),
                       hipMemcpyDeviceToDevice, stream);
        auto launch = [&](const float* sh, const int* si, const int* di,
                          const float* w0, const float* w1, float* dst, int E) {
            if (E <= 0) return;
            edge_scatter_kernel<<<(E + 3) / 4, 256, 0, stream>>>(sh, si, di, w0, w1, dst, E);
        };
        launch(paper_h,  wb_src, wb_dst, wb_w,     nullptr,  out_author, E_wb);
        launch(paper_h,  pi_src, pi_dst, pi_alpha, pi_w,     out_venue,  E_pi);
        launch(author_h, hp_src, hp_dst, hp_feat,  hp_alpha, out_venue,  E_hp);
        return;
    }

    // zero cursors + overflow count only (no output memsets needed)
    hipMemsetAsync(cnts, 0, zero_bytes, stream);

    // K1: full copy (blocks first) + bucket fill
    {
        const int copy_waves  = (n_paper + CPW - 1) / CPW;
        const int copy_blocks = (copy_waves * 64 + 255) / 256;
        const int fill_blocks = (E_tot + 255) / 256;
        fill_copy_kernel<<<copy_blocks + fill_blocks, 256, 0, stream>>>(
            wb_dst, wb_src, wb_w, E_wb,
            pi_dst, pi_src, pi_alpha, pi_w, E_pi,
            hp_dst, hp_src, hp_feat, hp_alpha, E_hp,
            n_author, n_venue, cnts, ameta, pmeta, hmeta, ovf_cnt, ovf,
            paper_h, out_paper, n_paper, copy_blocks);
    }

    // K2: gather (venue waves first, author waves backfill)
    {
        const long long total_waves = (long long)n_venue + n_author;
        const int blocks = (int)((total_waves * 64 + 255) / 256);
        gather_kernel<<<blocks, 256, 0, stream>>>(
            paper_h, author_h, cnts, ameta, pmeta, hmeta,
            out_author, out_venue, n_author, n_venue);
    }

    // K3: overflow tail (normally zero work)
    ovf_scatter_kernel<<<64, 256, 0, stream>>>(
        ovf_cnt, ovf, paper_h, author_h, out_author, out_venue, n_author, n_venue);
}